// Round 12
// baseline (413.650 us; speedup 1.0000x reference)
//
#include <hip/hip_runtime.h>
#include <math.h>

// ViT Vector Quantizer: z [32,1024,32] f32, embedding [8192,32] f32.
// Outputs (concat, read as f32): z_q_out [N*D], loss [1], idx [N] (as floats).
//
// R12: R8's proven argmin inner loop (83us @ 60% VALUBusy, best measured of
// R7-R11) with exactly two occupancy-side changes, plus fused epi:
//   K0 k_prep   : codebook normalize -> en, en_h, bf16 hi/lo B-frag swizzle;
//                 zero loss/tick.
//   K1 k_argmin : 512-thr blocks (8 waves), KSPLIT=2 -> grid (N/128, 2) = 512
//                 blocks = 2 blocks/CU = 4 waves/SIMD (2x R8's TLP; R8's 40%
//                 stall was 2-wave/SIMD latency exposure). Each block stages
//                 half the codebook (16 chunks x 32KB dbuf) -> staging halved.
//                 Inner loop IDENTICAL to R8: reg-prefetched B-frags, 2 indep
//                 MFMA chains (hh | hl->lh), packed-u32 top-2 (8-bit tile idx,
//                 quant 6.1e-5). Per-split u64 [s1q:26|s2q:25|8191-k:13];
//                 2-way ticket merge writes idx or -1 (gap < 2.5e-4).
//   K2 k_epi    : R10's proven fused epi: in-block exact fp32 rescore of
//                 flagged rows (thread-per-code), gather, STE out, idx, loss.

#define D 32
#define KCODES 8192
#define KSPLIT 2
#define NCHUNK 16           // chunks per split: 16 x 256 codes (16 tiles, 32 KB)
#define MASK8 0xFFFFFF00u   // keep 24 high bits; low 8 = (255 - tile_local)
#define MARGIN 2.5e-4f      // > 2*(quant 6.1e-5) + 2*(split-bf16 2.4e-5) + slack
#define EPS 1e-12f

typedef short bf16x8 __attribute__((ext_vector_type(8)));
typedef unsigned short u16x8 __attribute__((ext_vector_type(8)));
typedef float f32x4 __attribute__((ext_vector_type(4)));
typedef unsigned long long u64;

static __device__ __forceinline__ unsigned short f2bf(float x) {  // RNE bf16 bits
  unsigned u = __float_as_uint(x);
  return (unsigned short)((u + 0x7FFFu + ((u >> 16) & 1u)) >> 16);
}
static __device__ __forceinline__ float bf2f(unsigned short s) {
  return __uint_as_float(((unsigned)s) << 16);
}
static __device__ __forceinline__ void gload_lds16(const void* g, void* l) {
  __builtin_amdgcn_global_load_lds(
      (const __attribute__((address_space(1))) void*)g,
      (__attribute__((address_space(3))) void*)l, 16, 0, 0);
}

// MFMA fragment layouts (validated by R5-R11 exact-idx passes):
//   A[m][k]: m = lane&15, k = (lane>>4)*8 + j
//   B[k][n]: n = lane&15, k = (lane>>4)*8 + j
//   C[m][n]: n = lane&15, m = (lane>>4)*4 + reg

__global__ __launch_bounds__(256) void k_prep(const float* __restrict__ emb,
                                              float* __restrict__ en,
                                              float* __restrict__ en_h,
                                              unsigned short* __restrict__ eswz,
                                              float* __restrict__ loss,
                                              int* __restrict__ tick,
                                              int ntick) {
  int v = blockIdx.x * 256 + threadIdx.x;
  if (v == 0) *loss = 0.f;
  if (v < ntick) tick[v] = 0;
  if (v >= KCODES) return;

  float x[D];
  const float4* p = reinterpret_cast<const float4*>(emb + (size_t)v * D);
#pragma unroll
  for (int j = 0; j < D / 4; ++j) {
    float4 q = p[j];
    x[4 * j + 0] = q.x; x[4 * j + 1] = q.y; x[4 * j + 2] = q.z; x[4 * j + 3] = q.w;
  }
  float ss = 0.f;
#pragma unroll
  for (int j = 0; j < D; ++j) ss = fmaf(x[j], x[j], ss);
  float n = fmaxf(sqrtf(ss), EPS);
#pragma unroll
  for (int j = 0; j < D; ++j) x[j] = x[j] / n;   // true division mirrors reference

  float4* o = reinterpret_cast<float4*>(en + (size_t)v * D);
  float s2 = 0.f;
#pragma unroll
  for (int j = 0; j < D / 4; ++j) {
    float4 q = {x[4 * j], x[4 * j + 1], x[4 * j + 2], x[4 * j + 3]};
    s2 = fmaf(q.x, q.x, fmaf(q.y, q.y, fmaf(q.z, q.z, fmaf(q.w, q.w, s2))));
    o[j] = q;
  }
  en_h[v] = 0.5f * s2;

  unsigned short hi[D], lo[D];
#pragma unroll
  for (int j = 0; j < D; ++j) {
    hi[j] = f2bf(x[j]);
    lo[j] = f2bf(x[j] - bf2f(hi[j]));   // x - bf16(x) exact in fp32
  }
  int tl = v >> 4, m = v & 15;          // B-frag swizzle: tile = 1024 shorts
#pragma unroll
  for (int q = 0; q < 4; ++q) {
    u16x8 hv, lv;
#pragma unroll
    for (int j = 0; j < 8; ++j) { hv[j] = hi[8 * q + j]; lv[j] = lo[8 * q + j]; }
    *(u16x8*)(eswz + (size_t)tl * 1024 + (q * 16 + m) * 8) = hv;
    *(u16x8*)(eswz + (size_t)tl * 1024 + 512 + (q * 16 + m) * 8) = lv;
  }
}

// One tile: 2 independent MFMA chains + packed-u32 top-2 (R8's exact pattern).
#define TCOMP(BH, BL, TL)                                                      \
  {                                                                            \
    f32x4 aa = __builtin_amdgcn_mfma_f32_16x16x32_bf16(zhi, (BH), initc, 0, 0, 0); \
    f32x4 ab = __builtin_amdgcn_mfma_f32_16x16x32_bf16(zhi, (BL), zero4, 0, 0, 0); \
    ab = __builtin_amdgcn_mfma_f32_16x16x32_bf16(zlo, (BH), ab, 0, 0, 0);      \
    const unsigned t8 = (unsigned)(255 - (TL));                                \
    _Pragma("unroll") for (int r = 0; r < 4; ++r) {                            \
      float sa = aa[r] + ab[r];            /* positive -> bits order as uint */\
      unsigned q = (__float_as_uint(sa) & MASK8) | t8;                         \
      unsigned tm = min(q, p1[r]);                                             \
      p1[r] = max(q, p1[r]);                                                   \
      p2[r] = max(tm, p2[r]);                                                  \
    }                                                                          \
  }

// 512 thr = 8 waves (16 rows each); grid (N/128, 2) = 512 blocks = 2/CU.
__global__ __launch_bounds__(512, 4) void k_argmin(
    const float* __restrict__ z,
    const unsigned short* __restrict__ eswz,
    u64* __restrict__ mpp,              // [KSPLIT][N] packed per-split results
    int* __restrict__ tick,
    int* __restrict__ idx_ws, int N) {
  __shared__ unsigned short sbuf[2][16384];   // 2 x 32 KB double buffer
  __shared__ int s_old;

  const int tid = threadIdx.x;
  const int wid = tid >> 6, lane = tid & 63;
  const int lane15 = lane & 15, quad = lane >> 4;
  const int split = blockIdx.y;
  const int rowbase = blockIdx.x * 128 + wid * 16;   // this wave's 16 rows

  // stage chunk 0 (tiles split*256 .. +15) -- overlaps the z prologue
  const float4* gall =
      reinterpret_cast<const float4*>(eswz) + (size_t)(split * 256) * 128;
#pragma unroll
  for (int i = 0; i < 4; ++i) {
    int off = i * 512 + tid;                  // wave-uniform base + lane*16B
    gload_lds16(gall + off, (char*)&sbuf[0][0] + (size_t)off * 16);
  }

  // --- A-fragment: row = rowbase+lane15, dims quad*8..quad*8+7 (R8 prologue) ---
  bf16x8 zhi, zlo;
  {
    const float4* p =
        reinterpret_cast<const float4*>(z + (size_t)(rowbase + lane15) * D);
    float ss = 0.f;
#pragma unroll
    for (int j = 0; j < 8; ++j) {
      float4 q = p[j];
      ss = fmaf(q.x, q.x, fmaf(q.y, q.y, fmaf(q.z, q.z, fmaf(q.w, q.w, ss))));
    }
    float nn = fmaxf(sqrtf(ss), EPS);
    float4 a0 = p[quad * 2], a1 = p[quad * 2 + 1];
    float xs[8] = {a0.x / nn, a0.y / nn, a0.z / nn, a0.w / nn,
                   a1.x / nn, a1.y / nn, a1.z / nn, a1.w / nn};
#pragma unroll
    for (int j = 0; j < 8; ++j) {
      unsigned short h = f2bf(xs[j]);
      zhi[j] = (short)h;
      zlo[j] = (short)f2bf(xs[j] - bf2f(h));
    }
  }

  unsigned p1[4], p2[4];
#pragma unroll
  for (int r = 0; r < 4; ++r) { p1[r] = 0u; p2[r] = 0u; }
  const f32x4 initc = {1.25f, 1.25f, 1.25f, 1.25f};  // s' = 1.25 + dot > 0
  const f32x4 zero4 = {0.f, 0.f, 0.f, 0.f};

  for (int c = 0; c < NCHUNK; ++c) {
    __syncthreads();                 // buffer c&1 fully staged (vmcnt drained)
    if (c + 1 < NCHUNK) {            // next chunk's DMA overlaps this compute
      const float4* gn = gall + (size_t)(c + 1) * 2048;
      char* dst = (char*)&sbuf[(c + 1) & 1][0];
#pragma unroll
      for (int i = 0; i < 4; ++i) {
        int off = i * 512 + tid;
        gload_lds16(gn + off, dst + (size_t)off * 16);
      }
    }
    const unsigned short* buf = &sbuf[c & 1][0];
    bf16x8 Ah = *(const bf16x8*)(buf + lane * 8);
    bf16x8 Al = *(const bf16x8*)(buf + 512 + lane * 8);
#pragma unroll
    for (int t = 0; t < 16; t += 2) {
      bf16x8 Bh = *(const bf16x8*)(buf + (t + 1) * 1024 + lane * 8);
      bf16x8 Bl = *(const bf16x8*)(buf + (t + 1) * 1024 + 512 + lane * 8);
      TCOMP(Ah, Al, c * 16 + t);
      int tn = (t + 2) & 15;         // wraps on last pair: dummy reread of tile 0
      Ah = *(const bf16x8*)(buf + tn * 1024 + lane * 8);
      Al = *(const bf16x8*)(buf + tn * 1024 + 512 + lane * 8);
      TCOMP(Bh, Bl, c * 16 + t + 1);
    }
  }

  // --- cross-lane merge (16 lanes of each quad hold different codes) ---
#pragma unroll
  for (int r = 0; r < 4; ++r) {
    unsigned pv = p1[r];
    unsigned sb = pv & MASK8;
    int tile_local = 255 - (int)(pv & 255u);
    int kglobal = split * 4096 + tile_local * 16 + lane15;
    float s1f = __uint_as_float(sb);
    float s2f = __uint_as_float(p2[r] & MASK8);
    u64 pk = ((u64)sb << 32) | (unsigned)(8191 - kglobal);
#pragma unroll
    for (int m = 1; m <= 8; m <<= 1) {
      u64 op = __shfl_xor(pk, m, 64);
      float os1 = __shfl_xor(s1f, m, 64);
      float os2 = __shfl_xor(s2f, m, 64);
      s2f = fmaxf(fmaxf(s2f, os2), fminf(s1f, os1));  // union 2nd-best
      s1f = fmaxf(s1f, os1);
      pk = (op > pk) ? op : pk;                       // max s, tie -> min k
    }
    if (lane15 == 0) {
      int row = rowbase + quad * 4 + r;
      unsigned sbw = (unsigned)(pk >> 32);            // quantized s1 bits
      unsigned s2b = __float_as_uint(s2f);            // quantized s2 bits
      // pack [s1q:26 | s2q:25 | (8191-k):13]; s1-tie misorder only when
      // gap < 6.1e-5 << MARGIN -> such rows are flagged + rescored exactly.
      mpp[(size_t)split * N + row] =
          ((u64)(sbw >> 6) << 38) | ((u64)(s2b >> 7) << 13) | (pk & 8191u);
    }
  }

  // --- 2-way ticket: last split block for this row-block merges ---
  __threadfence();
  __syncthreads();
  if (tid == 0) s_old = atomicAdd(&tick[blockIdx.x], 1);
  __syncthreads();
  if (s_old != KSPLIT - 1) return;
  __threadfence();
  if (tid < 128) {
    int row = blockIdx.x * 128 + tid;
    u64 a = mpp[row];
    u64 b = mpp[(size_t)N + row];
    u64 B = (a > b) ? a : b;
    u64 L = (a > b) ? b : a;
    float s1g = __uint_as_float((unsigned)(B >> 38) << 6);
    float s2own = __uint_as_float((unsigned)((B >> 13) & 0x1FFFFFFu) << 7);
    float s2oth = __uint_as_float((unsigned)(L >> 38) << 6);
    float s2g = fmaxf(s2own, s2oth);
    int kb = 8191 - (int)(B & 8191u);
    idx_ws[row] = (s1g - s2g < MARGIN) ? -1 : kb;   // -1 => exact rescore in epi
  }
}

// Fused epilogue (R10's proven kernel): block exact-rescores its flagged rows
// (thread-per-code, coalesced), then gathers en[idx] and writes outputs.
__global__ __launch_bounds__(256) void k_epi(const float* __restrict__ z,
                                             const float* __restrict__ en,
                                             const float* __restrict__ en_h,
                                             const int* __restrict__ idx_ws,
                                             float* __restrict__ out_z,
                                             float* __restrict__ loss,
                                             float* __restrict__ out_idx,
                                             float scale) {
  __shared__ int nflag;
  __shared__ int flist[256];
  __shared__ int fres[256];
  __shared__ u64 wred[4];
  __shared__ float wsum[4];

  const int tid = threadIdx.x;
  const int lane = tid & 63, wid = tid >> 6;
  int row = blockIdx.x * 256 + tid;
  int kb = idx_ws[row];

  if (tid == 0) nflag = 0;
  __syncthreads();
  int myslot = -1;
  if (kb < 0) { myslot = atomicAdd(&nflag, 1); flist[myslot] = row; }
  __syncthreads();
  const int nf = nflag;

  for (int f = 0; f < nf; ++f) {            // uniform trip count -> safe syncs
    int frow = flist[f];
    const float* zr = z + (size_t)frow * D; // uniform -> scalar loads
    float v[D];
    float ss = 0.f;
#pragma unroll
    for (int d = 0; d < D; ++d) v[d] = zr[d];
#pragma unroll
    for (int d = 0; d < D; ++d) ss = fmaf(v[d], v[d], ss);
    float nn = fmaxf(sqrtf(ss), EPS);
#pragma unroll
    for (int d = 0; d < D; ++d) v[d] = v[d] / nn;

    u64 best = 0ull;
    for (int k = tid; k < KCODES; k += 256) {   // coalesced across threads
      const float4* er = reinterpret_cast<const float4*>(en + (size_t)k * D);
      float a = -en_h[k];
#pragma unroll
      for (int jj = 0; jj < 8; ++jj) {          // exact R4 fma order
        float4 e = er[jj];
        a = fmaf(v[4 * jj + 0], e.x, a);
        a = fmaf(v[4 * jj + 1], e.y, a);
        a = fmaf(v[4 * jj + 2], e.z, a);
        a = fmaf(v[4 * jj + 3], e.w, a);
      }
      unsigned o = __float_as_uint(a);
      o = (o & 0x80000000u) ? ~o : (o | 0x80000000u);
      u64 pk = ((u64)o << 32) | (unsigned)(8191 - k);
      best = (pk > best) ? pk : best;           // max s, tie -> min k
    }
#pragma unroll
    for (int m = 32; m >= 1; m >>= 1) {
      u64 op = __shfl_xor(best, m, 64);
      best = (op > best) ? op : best;
    }
    if (lane == 0) wred[wid] = best;
    __syncthreads();
    if (tid == 0) {
      u64 m01 = (wred[0] > wred[1]) ? wred[0] : wred[1];
      u64 m23 = (wred[2] > wred[3]) ? wred[2] : wred[3];
      u64 M = (m01 > m23) ? m01 : m23;
      fres[f] = 8191 - (int)(unsigned)(M & 0xFFFFFFFFull);
    }
    __syncthreads();
  }
  if (myslot >= 0) kb = fres[myslot];

  out_idx[row] = (float)kb;  // whole out buffer read back as f32

  const float4* p = reinterpret_cast<const float4*>(z + (size_t)row * D);
  float4 q[D / 4];
#pragma unroll
  for (int j = 0; j < D / 4; ++j) q[j] = p[j];
  float ss = 0.f;
#pragma unroll
  for (int j = 0; j < D / 4; ++j)
    ss = fmaf(q[j].x, q[j].x, fmaf(q[j].y, q[j].y, fmaf(q[j].z, q[j].z, fmaf(q[j].w, q[j].w, ss))));
  float n = fmaxf(sqrtf(ss), EPS);

  const float4* ep = reinterpret_cast<const float4*>(en + (size_t)kb * D);
  float4* op = reinterpret_cast<float4*>(out_z + (size_t)row * D);
  float s = 0.f;
#pragma unroll
  for (int j = 0; j < D / 4; ++j) {
    float4 e = ep[j];
    float4 o;
    o.x = q[j].x + (e.x - q[j].x);  // STE forward value, reference op order
    o.y = q[j].y + (e.y - q[j].y);
    o.z = q[j].z + (e.z - q[j].z);
    o.w = q[j].w + (e.w - q[j].w);
    op[j] = o;
    float dx = e.x - q[j].x / n;  float dy = e.y - q[j].y / n;
    float dz = e.z - q[j].z / n;  float dw = e.w - q[j].w / n;
    s = fmaf(dx, dx, fmaf(dy, dy, fmaf(dz, dz, fmaf(dw, dw, s))));
  }

#pragma unroll
  for (int off = 32; off > 0; off >>= 1) s += __shfl_down(s, off, 64);
  if (lane == 0) wsum[wid] = s;
  __syncthreads();
  if (tid == 0) {
    float tt = (wsum[0] + wsum[1]) + (wsum[2] + wsum[3]);
    atomicAdd(loss, tt * scale);
  }
}

extern "C" void kernel_launch(void* const* d_in, const int* in_sizes, int n_in,
                              void* d_out, int out_size, void* d_ws, size_t ws_size,
                              hipStream_t stream) {
  const float* z = (const float*)d_in[0];
  const float* emb = (const float*)d_in[1];
  const int N = in_sizes[0] / D;  // 32768
  const int K = in_sizes[1] / D;  // 8192

  float* out = (float*)d_out;
  float* out_z = out;                        // N*D
  float* loss = out + (size_t)N * D;         // 1
  float* out_idx = out + (size_t)N * D + 1;  // N

  // ws layout (~2.7 MB)
  char* w = (char*)d_ws;
  u64* mpp = (u64*)w;                            w += (size_t)KSPLIT * N * 8;  // 512 KB
  float* en = (float*)w;                         w += (size_t)K * D * 4;       // 1 MB
  float* en_h = (float*)w;                       w += (size_t)K * 4;           // 32 KB
  unsigned short* eswz = (unsigned short*)w;     w += (size_t)K * D * 2 * 2;   // 1 MB
  int* idx_ws = (int*)w;                         w += (size_t)N * 4;           // 128 KB
  int* tick = (int*)w;                           w += 1024;

  const int nrb = N / 128;   // 256 row-blocks

  k_prep<<<dim3(K / 256), 256, 0, stream>>>(emb, en, en_h, eswz, loss, tick, nrb);

  k_argmin<<<dim3(nrb, KSPLIT), 512, 0, stream>>>(z, eswz, mpp, tick, idx_ws, N);

  k_epi<<<dim3(N / 256), 256, 0, stream>>>(
      z, en, en_h, idx_ws, out_z, loss, out_idx, 1.25f / (float)((size_t)N * D));
}